// Round 8
// baseline (155.752 us; speedup 1.0000x reference)
//
#include <hip/hip_runtime.h>

#define TPB 256

typedef float f32x4 __attribute__((ext_vector_type(4)));

// Kernel 1: per-block expert histogram. blockHist[b*E + e] = count of expert e in block b's chunk.
__global__ void k_hist(const int* __restrict__ eidx, int* __restrict__ blockHist,
                       int NK, int E) {
    __shared__ int hist[256];
    int tid = threadIdx.x;
    for (int e = tid; e < E; e += TPB) hist[e] = 0;
    __syncthreads();
    int j = blockIdx.x * TPB + tid;
    if (j < NK) atomicAdd(&hist[eidx[j]], 1);
    __syncthreads();
    for (int e = tid; e < E; e += TPB)
        blockHist[(size_t)blockIdx.x * E + e] = hist[e];
}

// Kernel 2 (single block, 1024 threads): one flat expert-major scan.
// Thread t = (e = t/CH, chunk c = t%CH); chunk-sum over its blocks, Hillis-Steele
// inclusive scan over all E*CH chunk-sums (expert-major order == stable sort order),
// write back blockHist as GLOBAL flat exclusive prefixes (absorbs cross-expert
// offsets), emit inclusive per-expert cumsum as float.
__global__ void k_scan_all(int* __restrict__ blockHist, float* __restrict__ cumsum_out,
                           int numBlocks, int E, int CH) {
    __shared__ int s[1024];
    int t = threadIdx.x;
    int nT = E * CH;                       // <= 1024
    int e = t / CH, c = t % CH;
    int per = (numBlocks + CH - 1) / CH;
    int b0 = c * per;
    int b1 = b0 + per; if (b1 > numBlocks) b1 = numBlocks;
    int sum = 0;
    if (t < nT)
        for (int b = b0; b < b1; ++b) sum += blockHist[(size_t)b * E + e];
    s[t] = (t < nT) ? sum : 0;
    __syncthreads();
    for (int off = 1; off < 1024; off <<= 1) {
        int v = (t >= off) ? s[t - off] : 0;
        __syncthreads();
        s[t] += v;
        __syncthreads();
    }
    if (t < nT) {
        int run = s[t] - sum;              // flat exclusive prefix of my chunk
        for (int b = b0; b < b1; ++b) {
            size_t idx = (size_t)b * E + e;
            int v = blockHist[idx];
            blockHist[idx] = run;
            run += v;
        }
        if (c == CH - 1) cumsum_out[e] = (float)s[t];
    }
}

// Kernel 3: stable position via ballot match-any (rank within wave) + per-wave
// expert hist scanned across the block's 4 waves. blockHist already holds GLOBAL
// flat exclusive prefixes, so pos = blockHist[b][e] + wave_base + rank_in_wave.
// Writes expanded_row_idx (coalesced), expanded_scale (scattered), dstPos.
__global__ void __launch_bounds__(TPB) k_pos(
        const int* __restrict__ eidx, const float* __restrict__ scale,
        const int* __restrict__ blockHist,
        float* __restrict__ row_idx_out, float* __restrict__ scale_out,
        int* __restrict__ dstPos, int NK, int E, int K) {
    __shared__ int whist[4 * 256];
    __shared__ int wbase[4 * 256];
    int tid  = threadIdx.x;
    int j    = blockIdx.x * TPB + tid;
    int wv   = tid >> 6;
    int lane = tid & 63;

    for (int i = tid; i < 4 * E; i += TPB) whist[i] = 0;
    __syncthreads();

    bool valid = (j < NK);
    int e = valid ? eidx[j] : 0;

    // match-any over the wave: mask of lanes with equal e (E <= 256 -> 8 bits)
    unsigned long long mask = __ballot(valid);
    #pragma unroll
    for (int b = 0; b < 8; ++b) {
        unsigned long long bal = __ballot((e >> b) & 1);
        mask &= ((e >> b) & 1) ? bal : ~bal;
    }
    unsigned long long lt = (1ULL << lane) - 1ULL;
    int rank_in_wave = (int)__popcll(mask & lt);
    bool leader = valid && ((mask & lt) == 0);
    if (leader) whist[wv * E + e] = (int)__popcll(mask);
    __syncthreads();

    // exclusive scan of the 4 wave-hists per expert
    for (int ee = tid; ee < E; ee += TPB) {
        int base = 0;
        #pragma unroll
        for (int w = 0; w < 4; ++w) {
            wbase[w * E + ee] = base;
            base += whist[w * E + ee];
        }
    }
    __syncthreads();

    if (valid) {
        int pos = blockHist[(size_t)blockIdx.x * E + e] + wbase[wv * E + e] + rank_in_wave;
        row_idx_out[j] = (float)pos;
        dstPos[j] = pos;
        scale_out[pos] = scale[j / K];
    }
}

// Kernel 4: row SCATTER, one block per token (max MLP: tiny retire-fast blocks).
// Read x row once (coalesced), NT-store to K destination rows.
__global__ void k_scatter(const float* __restrict__ x, const int* __restrict__ dstPos,
                          float* __restrict__ out, int H, int K, int N) {
    __shared__ int pos_s[32];   // K <= 32
    int n4 = H >> 2;
    int tok = blockIdx.x;
    if (tok >= N) return;
    if (threadIdx.x < K) pos_s[threadIdx.x] = dstPos[tok * K + threadIdx.x];
    __syncthreads();
    const f32x4* xs = (const f32x4*)(x + (size_t)tok * H);
    for (int t = threadIdx.x; t < n4; t += blockDim.x) {
        f32x4 v = xs[t];
        #pragma unroll
        for (int k = 0; k < 8; ++k) {   // K == 8 here; guard keeps generality
            if (k < K) {
                f32x4* od = (f32x4*)(out + (size_t)pos_s[k] * H);
                __builtin_nontemporal_store(v, od + t);
            }
        }
    }
}

extern "C" void kernel_launch(void* const* d_in, const int* in_sizes, int n_in,
                              void* d_out, int out_size, void* d_ws, size_t ws_size,
                              hipStream_t stream) {
    const float* x     = (const float*)d_in[0];
    const int*   eidx  = (const int*)d_in[1];
    const float* scale = (const float*)d_in[2];

    const int N  = in_sizes[2];            // scale has N elements
    const int H  = in_sizes[0] / N;        // 1024
    const int K  = in_sizes[1] / N;        // 8
    const int NK = N * K;                  // 131072
    const int E  = out_size - (int)((long long)NK * H) - 2 * NK;   // 64

    const int numBlocks = (NK + TPB - 1) / TPB;  // 512

    // d_out layout (all float)
    float* out_x     = (float*)d_out;
    float* out_rowix = out_x + (size_t)NK * H;
    float* out_cum   = out_rowix + NK;
    float* out_scale = out_cum + E;

    // d_ws layout
    int* blockHist = (int*)d_ws;                        // numBlocks * E
    int* dstPos    = blockHist + (size_t)numBlocks * E; // NK

    int CH = 1024 / E; if (CH < 1) CH = 1;              // chunks per expert

    k_hist<<<numBlocks, TPB, 0, stream>>>(eidx, blockHist, NK, E);
    k_scan_all<<<1, 1024, 0, stream>>>(blockHist, out_cum, numBlocks, E, CH);
    k_pos<<<numBlocks, TPB, 0, stream>>>(eidx, scale, blockHist,
                                         out_rowix, out_scale, dstPos, NK, E, K);
    k_scatter<<<N, TPB, 0, stream>>>(x, dstPos, out_x, H, K, N);
}

// Round 10
// 142.928 us; speedup vs baseline: 1.0897x; 1.0897x over previous
//
#include <hip/hip_runtime.h>

#define TPB 256

typedef float f32x4 __attribute__((ext_vector_type(4)));

// Kernel 1: per-block expert histogram. blockHist[b*E + e] = count of expert e in block b's chunk.
__global__ void k_hist(const int* __restrict__ eidx, int* __restrict__ blockHist,
                       int NK, int E) {
    __shared__ int hist[256];
    int tid = threadIdx.x;
    for (int e = tid; e < E; e += TPB) hist[e] = 0;
    __syncthreads();
    int j = blockIdx.x * TPB + tid;
    if (j < NK) atomicAdd(&hist[eidx[j]], 1);
    __syncthreads();
    for (int e = tid; e < E; e += TPB)
        blockHist[(size_t)blockIdx.x * E + e] = hist[e];
}

// Kernel 2a: one block per expert — parallel exclusive scan of that expert's
// per-block counts. Per-thread serial chains are length ceil(numBlocks/TPB)=2,
// so cross-XCD L2 latency is hidden by 64x256 parallelism (R8 lesson: the
// single-block fused scan serialized ~32-long dependent chains -> ~28us).
__global__ void k_scan_blocks(int* __restrict__ blockHist, int* __restrict__ counts,
                              int numBlocks, int E) {
    __shared__ int s[TPB];
    int e = blockIdx.x;
    int tid = threadIdx.x;
    int per = (numBlocks + TPB - 1) / TPB;
    int start = tid * per;
    int end = start + per; if (end > numBlocks) end = numBlocks;
    int sum = 0;
    for (int b = start; b < end; ++b) sum += blockHist[(size_t)b * E + e];
    s[tid] = sum;
    __syncthreads();
    for (int off = 1; off < TPB; off <<= 1) {
        int t = (tid >= off) ? s[tid - off] : 0;
        __syncthreads();
        s[tid] += t;
        __syncthreads();
    }
    int run = (tid == 0) ? 0 : s[tid - 1];
    if (tid == TPB - 1) counts[e] = s[tid];
    for (int b = start; b < end; ++b) {
        size_t idx = (size_t)b * E + e;
        int v = blockHist[idx];
        blockHist[idx] = run;
        run += v;
    }
}

// Kernel 2b (1 wave): cross-expert exclusive scan -> offsets; inclusive cumsum (float).
__global__ void k_scan_experts(const int* __restrict__ counts, int* __restrict__ offsets,
                               float* __restrict__ cumsum_out, int E) {
    if (threadIdx.x == 0) {
        int run = 0;
        for (int e = 0; e < E; ++e) {
            offsets[e] = run;
            run += counts[e];
            cumsum_out[e] = (float)run;
        }
    }
}

// Kernel 3: stable position via ballot match-any (rank within wave, by lane order)
// + per-wave expert hist scanned across the block's 4 waves (by wave order).
// pos = offsets[e] + blockPrefix[b][e] + wave_base + rank_in_wave  — exactly the
// stable-sort position. Writes expanded_row_idx (coalesced), expanded_scale
// (scattered), dstPos.
__global__ void __launch_bounds__(TPB) k_pos(
        const int* __restrict__ eidx, const float* __restrict__ scale,
        const int* __restrict__ blockHist, const int* __restrict__ offsets,
        float* __restrict__ row_idx_out, float* __restrict__ scale_out,
        int* __restrict__ dstPos, int NK, int E, int K) {
    __shared__ int whist[4 * 256];
    __shared__ int wbase[4 * 256];
    int tid  = threadIdx.x;
    int j    = blockIdx.x * TPB + tid;
    int wv   = tid >> 6;
    int lane = tid & 63;

    for (int i = tid; i < 4 * E; i += TPB) whist[i] = 0;
    __syncthreads();

    bool valid = (j < NK);
    int e = valid ? eidx[j] : 0;

    // match-any over the wave: mask of lanes with equal e (E <= 256 -> 8 bits)
    unsigned long long mask = __ballot(valid);
    #pragma unroll
    for (int b = 0; b < 8; ++b) {
        unsigned long long bal = __ballot((e >> b) & 1);
        mask &= ((e >> b) & 1) ? bal : ~bal;
    }
    unsigned long long lt = (1ULL << lane) - 1ULL;
    int rank_in_wave = (int)__popcll(mask & lt);
    bool leader = valid && ((mask & lt) == 0);
    if (leader) whist[wv * E + e] = (int)__popcll(mask);
    __syncthreads();

    for (int ee = tid; ee < E; ee += TPB) {
        int base = 0;
        #pragma unroll
        for (int w = 0; w < 4; ++w) {
            wbase[w * E + ee] = base;
            base += whist[w * E + ee];
        }
    }
    __syncthreads();

    if (valid) {
        int pos = offsets[e] + blockHist[(size_t)blockIdx.x * E + e]
                + wbase[wv * E + e] + rank_in_wave;
        row_idx_out[j] = (float)pos;
        dstPos[j] = pos;
        scale_out[pos] = scale[j / K];
    }
}

// Kernel 4: row SCATTER, one block per token (max MLP: tiny retire-fast blocks).
// NT load (row read exactly once -> don't pollute L2), NT stores to K dest rows.
__global__ void k_scatter(const float* __restrict__ x, const int* __restrict__ dstPos,
                          float* __restrict__ out, int H, int K, int N) {
    __shared__ int pos_s[32];   // K <= 32
    int n4 = H >> 2;
    int tok = blockIdx.x;
    if (tok >= N) return;
    if (threadIdx.x < K) pos_s[threadIdx.x] = dstPos[tok * K + threadIdx.x];
    __syncthreads();
    const f32x4* xs = (const f32x4*)(x + (size_t)tok * H);
    for (int t = threadIdx.x; t < n4; t += blockDim.x) {
        f32x4 v = __builtin_nontemporal_load(xs + t);
        #pragma unroll
        for (int k = 0; k < 8; ++k) {   // K == 8 here; guard keeps generality
            if (k < K) {
                f32x4* od = (f32x4*)(out + (size_t)pos_s[k] * H);
                __builtin_nontemporal_store(v, od + t);
            }
        }
    }
}

extern "C" void kernel_launch(void* const* d_in, const int* in_sizes, int n_in,
                              void* d_out, int out_size, void* d_ws, size_t ws_size,
                              hipStream_t stream) {
    const float* x     = (const float*)d_in[0];
    const int*   eidx  = (const int*)d_in[1];
    const float* scale = (const float*)d_in[2];

    const int N  = in_sizes[2];            // scale has N elements
    const int H  = in_sizes[0] / N;        // 1024
    const int K  = in_sizes[1] / N;        // 8
    const int NK = N * K;                  // 131072
    const int E  = out_size - (int)((long long)NK * H) - 2 * NK;   // 64

    const int numBlocks = (NK + TPB - 1) / TPB;  // 512

    // d_out layout (all float)
    float* out_x     = (float*)d_out;
    float* out_rowix = out_x + (size_t)NK * H;
    float* out_cum   = out_rowix + NK;
    float* out_scale = out_cum + E;

    // d_ws layout
    int* blockHist = (int*)d_ws;                        // numBlocks * E
    int* counts    = blockHist + (size_t)numBlocks * E; // E
    int* offsets   = counts + E;                        // E
    int* dstPos    = offsets + E;                       // NK

    k_hist<<<numBlocks, TPB, 0, stream>>>(eidx, blockHist, NK, E);
    k_scan_blocks<<<E, TPB, 0, stream>>>(blockHist, counts, numBlocks, E);
    k_scan_experts<<<1, 64, 0, stream>>>(counts, offsets, out_cum, E);
    k_pos<<<numBlocks, TPB, 0, stream>>>(eidx, scale, blockHist, offsets,
                                         out_rowix, out_scale, dstPos, NK, E, K);
    k_scatter<<<N, TPB, 0, stream>>>(x, dstPos, out_x, H, K, N);
}

// Round 11
// 124.600 us; speedup vs baseline: 1.2500x; 1.1471x over previous
//
#include <hip/hip_runtime.h>

#define TPB 256

typedef float f32x4 __attribute__((ext_vector_type(4)));

// Kernel 1: per-block expert histogram. blockHist[b*E + e] = count of expert e in block b's chunk.
__global__ void k_hist(const int* __restrict__ eidx, int* __restrict__ blockHist,
                       int NK, int E) {
    __shared__ int hist[256];
    int tid = threadIdx.x;
    for (int e = tid; e < E; e += TPB) hist[e] = 0;
    __syncthreads();
    int j = blockIdx.x * TPB + tid;
    if (j < NK) atomicAdd(&hist[eidx[j]], 1);
    __syncthreads();
    for (int e = tid; e < E; e += TPB)
        blockHist[(size_t)blockIdx.x * E + e] = hist[e];
}

// Kernel 2a: one block per expert — parallel exclusive scan of that expert's
// per-block counts. Per-thread serial chains are length ceil(numBlocks/TPB)=2,
// so cross-XCD L2 latency is hidden by 64x256 parallelism (R8 lesson: the
// single-block fused scan serialized ~32-long dependent chains -> ~28us).
__global__ void k_scan_blocks(int* __restrict__ blockHist, int* __restrict__ counts,
                              int numBlocks, int E) {
    __shared__ int s[TPB];
    int e = blockIdx.x;
    int tid = threadIdx.x;
    int per = (numBlocks + TPB - 1) / TPB;
    int start = tid * per;
    int end = start + per; if (end > numBlocks) end = numBlocks;
    int sum = 0;
    for (int b = start; b < end; ++b) sum += blockHist[(size_t)b * E + e];
    s[tid] = sum;
    __syncthreads();
    for (int off = 1; off < TPB; off <<= 1) {
        int t = (tid >= off) ? s[tid - off] : 0;
        __syncthreads();
        s[tid] += t;
        __syncthreads();
    }
    int run = (tid == 0) ? 0 : s[tid - 1];
    if (tid == TPB - 1) counts[e] = s[tid];
    for (int b = start; b < end; ++b) {
        size_t idx = (size_t)b * E + e;
        int v = blockHist[idx];
        blockHist[idx] = run;
        run += v;
    }
}

// Kernel 2b (1 wave): cross-expert exclusive scan -> offsets; inclusive cumsum (float).
__global__ void k_scan_experts(const int* __restrict__ counts, int* __restrict__ offsets,
                               float* __restrict__ cumsum_out, int E) {
    if (threadIdx.x == 0) {
        int run = 0;
        for (int e = 0; e < E; ++e) {
            offsets[e] = run;
            run += counts[e];
            cumsum_out[e] = (float)run;
        }
    }
}

// Kernel 3: stable position via ballot match-any (rank within wave, by lane order)
// + per-wave expert hist scanned across the block's 4 waves (by wave order).
// pos = offsets[e] + blockPrefix[b][e] + wave_base + rank_in_wave.
__global__ void __launch_bounds__(TPB) k_pos(
        const int* __restrict__ eidx, const float* __restrict__ scale,
        const int* __restrict__ blockHist, const int* __restrict__ offsets,
        float* __restrict__ row_idx_out, float* __restrict__ scale_out,
        int* __restrict__ dstPos, int NK, int E, int K) {
    __shared__ int whist[4 * 256];
    __shared__ int wbase[4 * 256];
    int tid  = threadIdx.x;
    int j    = blockIdx.x * TPB + tid;
    int wv   = tid >> 6;
    int lane = tid & 63;

    for (int i = tid; i < 4 * E; i += TPB) whist[i] = 0;
    __syncthreads();

    bool valid = (j < NK);
    int e = valid ? eidx[j] : 0;

    // match-any over the wave: mask of lanes with equal e (E <= 256 -> 8 bits)
    unsigned long long mask = __ballot(valid);
    #pragma unroll
    for (int b = 0; b < 8; ++b) {
        unsigned long long bal = __ballot((e >> b) & 1);
        mask &= ((e >> b) & 1) ? bal : ~bal;
    }
    unsigned long long lt = (1ULL << lane) - 1ULL;
    int rank_in_wave = (int)__popcll(mask & lt);
    bool leader = valid && ((mask & lt) == 0);
    if (leader) whist[wv * E + e] = (int)__popcll(mask);
    __syncthreads();

    for (int ee = tid; ee < E; ee += TPB) {
        int base = 0;
        #pragma unroll
        for (int w = 0; w < 4; ++w) {
            wbase[w * E + ee] = base;
            base += whist[w * E + ee];
        }
    }
    __syncthreads();

    if (valid) {
        int pos = offsets[e] + blockHist[(size_t)blockIdx.x * E + e]
                + wbase[wv * E + e] + rank_in_wave;
        row_idx_out[j] = (float)pos;
        dstPos[j] = pos;
        scale_out[pos] = scale[j / K];
    }
}

// Kernel 4: row SCATTER, one block per token (max MLP: tiny retire-fast blocks).
// PLAIN load for x (R10 lesson: NT load cost +15us — row lines are shared across
// the block's waves and want L2 hits), NT stores for the 537MB write stream.
// Row element prefetched into a register before the barrier to overlap the
// x load with the dstPos load.
__global__ void k_scatter(const float* __restrict__ x, const int* __restrict__ dstPos,
                          float* __restrict__ out, int H, int K, int N) {
    __shared__ int pos_s[32];   // K <= 32
    int n4 = H >> 2;
    int tok = blockIdx.x;
    if (tok >= N) return;
    const f32x4* xs = (const f32x4*)(x + (size_t)tok * H);
    int tid = threadIdx.x;
    f32x4 v0;
    bool have0 = (tid < n4);
    if (have0) v0 = xs[tid];                 // issue row load before barrier
    if (tid < K) pos_s[tid] = dstPos[tok * K + tid];
    __syncthreads();
    for (int t = tid; t < n4; t += blockDim.x) {
        f32x4 v = (t == tid) ? v0 : xs[t];
        #pragma unroll
        for (int k = 0; k < 8; ++k) {   // K == 8 here; guard keeps generality
            if (k < K) {
                f32x4* od = (f32x4*)(out + (size_t)pos_s[k] * H);
                __builtin_nontemporal_store(v, od + t);
            }
        }
    }
}

extern "C" void kernel_launch(void* const* d_in, const int* in_sizes, int n_in,
                              void* d_out, int out_size, void* d_ws, size_t ws_size,
                              hipStream_t stream) {
    const float* x     = (const float*)d_in[0];
    const int*   eidx  = (const int*)d_in[1];
    const float* scale = (const float*)d_in[2];

    const int N  = in_sizes[2];            // scale has N elements
    const int H  = in_sizes[0] / N;        // 1024
    const int K  = in_sizes[1] / N;        // 8
    const int NK = N * K;                  // 131072
    const int E  = out_size - (int)((long long)NK * H) - 2 * NK;   // 64

    const int numBlocks = (NK + TPB - 1) / TPB;  // 512

    // d_out layout (all float)
    float* out_x     = (float*)d_out;
    float* out_rowix = out_x + (size_t)NK * H;
    float* out_cum   = out_rowix + NK;
    float* out_scale = out_cum + E;

    // d_ws layout
    int* blockHist = (int*)d_ws;                        // numBlocks * E
    int* counts    = blockHist + (size_t)numBlocks * E; // E
    int* offsets   = counts + E;                        // E
    int* dstPos    = offsets + E;                       // NK

    k_hist<<<numBlocks, TPB, 0, stream>>>(eidx, blockHist, NK, E);
    k_scan_blocks<<<E, TPB, 0, stream>>>(blockHist, counts, numBlocks, E);
    k_scan_experts<<<1, 64, 0, stream>>>(counts, offsets, out_cum, E);
    k_pos<<<numBlocks, TPB, 0, stream>>>(eidx, scale, blockHist, offsets,
                                         out_rowix, out_scale, dstPos, NK, E, K);
    k_scatter<<<N, TPB, 0, stream>>>(x, dstPos, out_x, H, K, N);
}

// Round 13
// 121.303 us; speedup vs baseline: 1.2840x; 1.0272x over previous
//
#include <hip/hip_runtime.h>

#define TPB 256

typedef float f32x4 __attribute__((ext_vector_type(4)));

// Kernel 1: per-block expert histogram. blockHist[b*E + e] = count of expert e in block b's chunk.
__global__ void k_hist(const int* __restrict__ eidx, int* __restrict__ blockHist,
                       int NK, int E) {
    __shared__ int hist[256];
    int tid = threadIdx.x;
    for (int e = tid; e < E; e += TPB) hist[e] = 0;
    __syncthreads();
    int j = blockIdx.x * TPB + tid;
    if (j < NK) atomicAdd(&hist[eidx[j]], 1);
    __syncthreads();
    for (int e = tid; e < E; e += TPB)
        blockHist[(size_t)blockIdx.x * E + e] = hist[e];
}

// Kernel 2: one block per expert — parallel exclusive scan of that expert's
// per-block counts (in place); per-expert total -> counts[e]. Serial chains are
// length ceil(numBlocks/TPB)=2 (R8 lesson: long dependent global chains kill).
__global__ void k_scan_blocks(int* __restrict__ blockHist, int* __restrict__ counts,
                              int numBlocks, int E) {
    __shared__ int s[TPB];
    int e = blockIdx.x;
    int tid = threadIdx.x;
    int per = (numBlocks + TPB - 1) / TPB;
    int start = tid * per;
    int end = start + per; if (end > numBlocks) end = numBlocks;
    int sum = 0;
    for (int b = start; b < end; ++b) sum += blockHist[(size_t)b * E + e];
    s[tid] = sum;
    __syncthreads();
    for (int off = 1; off < TPB; off <<= 1) {
        int t = (tid >= off) ? s[tid - off] : 0;
        __syncthreads();
        s[tid] += t;
        __syncthreads();
    }
    int run = (tid == 0) ? 0 : s[tid - 1];
    if (tid == TPB - 1) counts[e] = s[tid];
    for (int b = start; b < end; ++b) {
        size_t idx = (size_t)b * E + e;
        int v = blockHist[idx];
        blockHist[idx] = run;
        run += v;
    }
}

// Kernel 3: stable position. Each block (a) scans counts[E] in LDS for the
// cross-expert exclusive offsets (E<=256, Hillis-Steele, ~free; kills the old
// 1-thread k_scan_experts kernel + its launch gap), (b) ballot match-any rank
// within wave + per-wave hist scanned across the 4 waves.
// pos = off(e) + blockPrefix[b][e] + wave_base + rank_in_wave.
// Block 0 also emits the float inclusive cumsum output.
__global__ void __launch_bounds__(TPB) k_pos(
        const int* __restrict__ eidx, const float* __restrict__ scale,
        const int* __restrict__ blockHist, const int* __restrict__ counts,
        float* __restrict__ row_idx_out, float* __restrict__ scale_out,
        float* __restrict__ cumsum_out, int* __restrict__ dstPos,
        int NK, int E, int K) {
    __shared__ int whist[4 * 256];
    __shared__ int wbase[4 * 256];
    __shared__ int cnt_sh[256];
    __shared__ int inc_sh[256];
    int tid  = threadIdx.x;
    int j    = blockIdx.x * TPB + tid;
    int wv   = tid >> 6;
    int lane = tid & 63;

    for (int i = tid; i < 4 * E; i += TPB) whist[i] = 0;
    if (tid < E) { int c = counts[tid]; cnt_sh[tid] = c; inc_sh[tid] = c; }
    __syncthreads();

    // inclusive scan of counts over E elements (E <= 256)
    for (int off = 1; off < E; off <<= 1) {
        int v = 0;
        if (tid < E && tid >= off) v = inc_sh[tid - off];
        __syncthreads();
        if (tid < E) inc_sh[tid] += v;
        __syncthreads();
    }
    if (blockIdx.x == 0 && tid < E) cumsum_out[tid] = (float)inc_sh[tid];

    bool valid = (j < NK);
    int e = valid ? eidx[j] : 0;

    // match-any over the wave: mask of lanes with equal e (E <= 256 -> 8 bits)
    unsigned long long mask = __ballot(valid);
    #pragma unroll
    for (int b = 0; b < 8; ++b) {
        unsigned long long bal = __ballot((e >> b) & 1);
        mask &= ((e >> b) & 1) ? bal : ~bal;
    }
    unsigned long long lt = (1ULL << lane) - 1ULL;
    int rank_in_wave = (int)__popcll(mask & lt);
    bool leader = valid && ((mask & lt) == 0);
    if (leader) whist[wv * E + e] = (int)__popcll(mask);
    __syncthreads();

    for (int ee = tid; ee < E; ee += TPB) {
        int base = 0;
        #pragma unroll
        for (int w = 0; w < 4; ++w) {
            wbase[w * E + ee] = base;
            base += whist[w * E + ee];
        }
    }
    __syncthreads();

    if (valid) {
        int off_e = inc_sh[e] - cnt_sh[e];   // exclusive cross-expert offset
        int pos = off_e + blockHist[(size_t)blockIdx.x * E + e]
                + wbase[wv * E + e] + rank_in_wave;
        row_idx_out[j] = (float)pos;
        dstPos[j] = pos;
        scale_out[pos] = scale[j / K];
    }
}

// Kernel 4: row SCATTER, one block per token (max MLP: tiny retire-fast blocks).
// PLAIN load for x (R10 lesson: NT load cost +15us), NT stores for the 537MB
// write stream. Row element prefetched before the barrier.
__global__ void k_scatter(const float* __restrict__ x, const int* __restrict__ dstPos,
                          float* __restrict__ out, int H, int K, int N) {
    __shared__ int pos_s[32];   // K <= 32
    int n4 = H >> 2;
    int tok = blockIdx.x;
    if (tok >= N) return;
    const f32x4* xs = (const f32x4*)(x + (size_t)tok * H);
    int tid = threadIdx.x;
    f32x4 v0;
    bool have0 = (tid < n4);
    if (have0) v0 = xs[tid];                 // issue row load before barrier
    if (tid < K) pos_s[tid] = dstPos[tok * K + tid];
    __syncthreads();
    for (int t = tid; t < n4; t += blockDim.x) {
        f32x4 v = (t == tid) ? v0 : xs[t];
        #pragma unroll
        for (int k = 0; k < 8; ++k) {   // K == 8 here; guard keeps generality
            if (k < K) {
                f32x4* od = (f32x4*)(out + (size_t)pos_s[k] * H);
                __builtin_nontemporal_store(v, od + t);
            }
        }
    }
}

extern "C" void kernel_launch(void* const* d_in, const int* in_sizes, int n_in,
                              void* d_out, int out_size, void* d_ws, size_t ws_size,
                              hipStream_t stream) {
    const float* x     = (const float*)d_in[0];
    const int*   eidx  = (const int*)d_in[1];
    const float* scale = (const float*)d_in[2];

    const int N  = in_sizes[2];            // scale has N elements
    const int H  = in_sizes[0] / N;        // 1024
    const int K  = in_sizes[1] / N;        // 8
    const int NK = N * K;                  // 131072
    const int E  = out_size - (int)((long long)NK * H) - 2 * NK;   // 64

    const int numBlocks = (NK + TPB - 1) / TPB;  // 512

    // d_out layout (all float)
    float* out_x     = (float*)d_out;
    float* out_rowix = out_x + (size_t)NK * H;
    float* out_cum   = out_rowix + NK;
    float* out_scale = out_cum + E;

    // d_ws layout
    int* blockHist = (int*)d_ws;                        // numBlocks * E
    int* counts    = blockHist + (size_t)numBlocks * E; // E
    int* dstPos    = counts + E;                        // NK

    k_hist<<<numBlocks, TPB, 0, stream>>>(eidx, blockHist, NK, E);
    k_scan_blocks<<<E, TPB, 0, stream>>>(blockHist, counts, numBlocks, E);
    k_pos<<<numBlocks, TPB, 0, stream>>>(eidx, scale, blockHist, counts,
                                         out_rowix, out_scale, out_cum, dstPos,
                                         NK, E, K);
    k_scatter<<<N, TPB, 0, stream>>>(x, dstPos, out_x, H, K, N);
}

// Round 14
// 118.543 us; speedup vs baseline: 1.3139x; 1.0233x over previous
//
#include <hip/hip_runtime.h>

#define TPB 256

typedef float f32x4 __attribute__((ext_vector_type(4)));

// Kernel 1: per-block expert histogram over 256-slot chunks.
__global__ void k_hist(const int* __restrict__ eidx, int* __restrict__ blockHist,
                       int NK, int E) {
    __shared__ int hist[256];
    int tid = threadIdx.x;
    for (int e = tid; e < E; e += TPB) hist[e] = 0;
    __syncthreads();
    int j = blockIdx.x * TPB + tid;
    if (j < NK) atomicAdd(&hist[eidx[j]], 1);
    __syncthreads();
    for (int e = tid; e < E; e += TPB)
        blockHist[(size_t)blockIdx.x * E + e] = hist[e];
}

// Kernel 2: one block per expert — parallel exclusive scan of that expert's
// per-chunk counts (in place); per-expert total -> counts[e]. Serial chains are
// length ceil(numBlocks/TPB)=2 (R8 lesson: long dependent global chains kill).
__global__ void k_scan_blocks(int* __restrict__ blockHist, int* __restrict__ counts,
                              int numBlocks, int E) {
    __shared__ int s[TPB];
    int e = blockIdx.x;
    int tid = threadIdx.x;
    int per = (numBlocks + TPB - 1) / TPB;
    int start = tid * per;
    int end = start + per; if (end > numBlocks) end = numBlocks;
    int sum = 0;
    for (int b = start; b < end; ++b) sum += blockHist[(size_t)b * E + e];
    s[tid] = sum;
    __syncthreads();
    for (int off = 1; off < TPB; off <<= 1) {
        int t = (tid >= off) ? s[tid - off] : 0;
        __syncthreads();
        s[tid] += t;
        __syncthreads();
    }
    int run = (tid == 0) ? 0 : s[tid - 1];
    if (tid == TPB - 1) counts[e] = s[tid];
    for (int b = start; b < end; ++b) {
        size_t idx = (size_t)b * E + e;
        int v = blockHist[idx];
        blockHist[idx] = run;
        run += v;
    }
}

// Kernel 3: FUSED pos + scatter, one block per TOKEN (16384 retire-fast blocks —
// R7 lesson: fusion at 512 looping blocks kills MLP; this keeps R6 geometry).
// Each block: (a) issue its x-row load first (latency hidden under rank compute),
// (b) recompute its 256-slot chunk's stable ranks via ballot match-any + LDS
// scans (32 chunk-mate blocks do this redundantly — ~16% ALU, hidden under the
// write-bus-bound scatter), (c) write its own 8 slots' row_idx/scale, (d) NT-store
// the row to its K destination rows. Kills k_pos dispatch + dstPos round-trip.
__global__ void __launch_bounds__(TPB) k_pos_scatter(
        const int* __restrict__ eidx, const float* __restrict__ scale,
        const int* __restrict__ blockHist, const int* __restrict__ counts,
        const float* __restrict__ x,
        float* __restrict__ row_idx_out, float* __restrict__ scale_out,
        float* __restrict__ cumsum_out, float* __restrict__ out_x,
        int NK, int E, int K, int H) {
    __shared__ int whist[4 * 256];
    __shared__ int wbase[4 * 256];
    __shared__ int cnt_sh[256];
    __shared__ int inc_sh[256];
    __shared__ int pos_sh[TPB];
    int tid  = threadIdx.x;
    int tok  = blockIdx.x;
    int tpc  = TPB / K;                    // tokens per 256-slot chunk
    int chunk = tok / tpc;
    int j    = chunk * TPB + tid;          // flat slot this thread ranks
    int wv   = tid >> 6;
    int lane = tid & 63;

    // (a) issue x-row load early; rank compute hides the HBM latency
    const f32x4* xs = (const f32x4*)(x + (size_t)tok * H);
    int n4 = H >> 2;
    f32x4 v0;
    bool have0 = (tid < n4);
    if (have0) v0 = xs[tid];

    for (int i = tid; i < 4 * E; i += TPB) whist[i] = 0;
    if (tid < E) { int c = counts[tid]; cnt_sh[tid] = c; inc_sh[tid] = c; }
    __syncthreads();

    // inclusive scan of counts over E elements (E <= 256)
    for (int off = 1; off < E; off <<= 1) {
        int v = 0;
        if (tid < E && tid >= off) v = inc_sh[tid - off];
        __syncthreads();
        if (tid < E) inc_sh[tid] += v;
        __syncthreads();
    }
    if (blockIdx.x == 0 && tid < E) cumsum_out[tid] = (float)inc_sh[tid];

    bool valid = (j < NK);
    int e = valid ? eidx[j] : 0;

    // match-any over the wave: mask of lanes with equal e (E <= 256 -> 8 bits)
    unsigned long long mask = __ballot(valid);
    #pragma unroll
    for (int b = 0; b < 8; ++b) {
        unsigned long long bal = __ballot((e >> b) & 1);
        mask &= ((e >> b) & 1) ? bal : ~bal;
    }
    unsigned long long lt = (1ULL << lane) - 1ULL;
    int rank_in_wave = (int)__popcll(mask & lt);
    bool leader = valid && ((mask & lt) == 0);
    if (leader) whist[wv * E + e] = (int)__popcll(mask);
    __syncthreads();

    for (int ee = tid; ee < E; ee += TPB) {
        int base = 0;
        #pragma unroll
        for (int w = 0; w < 4; ++w) {
            wbase[w * E + ee] = base;
            base += whist[w * E + ee];
        }
    }
    __syncthreads();

    if (valid) {
        int off_e = inc_sh[e] - cnt_sh[e];   // exclusive cross-expert offset
        pos_sh[tid] = off_e + blockHist[(size_t)chunk * E + e]
                    + wbase[wv * E + e] + rank_in_wave;
    }
    __syncthreads();

    // (c) this block owns slots [s0, s0+K) of the chunk — write row_idx/scale
    int s0 = (tok - chunk * tpc) * K;
    if (tid < K) {
        int jj = chunk * TPB + s0 + tid;
        if (jj < NK) {
            int p = pos_sh[s0 + tid];
            row_idx_out[jj] = (float)p;
            scale_out[p] = scale[tok];
        }
    }

    // (d) scatter: read row once (plain loads — R10: NT loads cost +15us),
    // NT-store to K destination rows (keep 537MB stream out of L2).
    if ((size_t)tok * K < (size_t)NK) {
        for (int t = tid; t < n4; t += TPB) {
            f32x4 v = (t == tid) ? v0 : xs[t];
            #pragma unroll
            for (int k = 0; k < 8; ++k) {   // K == 8 here; guard keeps generality
                if (k < K) {
                    f32x4* od = (f32x4*)(out_x + (size_t)pos_sh[s0 + k] * H);
                    __builtin_nontemporal_store(v, od + t);
                }
            }
        }
    }
}

extern "C" void kernel_launch(void* const* d_in, const int* in_sizes, int n_in,
                              void* d_out, int out_size, void* d_ws, size_t ws_size,
                              hipStream_t stream) {
    const float* x     = (const float*)d_in[0];
    const int*   eidx  = (const int*)d_in[1];
    const float* scale = (const float*)d_in[2];

    const int N  = in_sizes[2];            // scale has N elements
    const int H  = in_sizes[0] / N;        // 1024
    const int K  = in_sizes[1] / N;        // 8
    const int NK = N * K;                  // 131072
    const int E  = out_size - (int)((long long)NK * H) - 2 * NK;   // 64

    const int numBlocks = (NK + TPB - 1) / TPB;  // 512 chunks

    // d_out layout (all float)
    float* out_x     = (float*)d_out;
    float* out_rowix = out_x + (size_t)NK * H;
    float* out_cum   = out_rowix + NK;
    float* out_scale = out_cum + E;

    // d_ws layout
    int* blockHist = (int*)d_ws;                        // numBlocks * E
    int* counts    = blockHist + (size_t)numBlocks * E; // E

    k_hist<<<numBlocks, TPB, 0, stream>>>(eidx, blockHist, NK, E);
    k_scan_blocks<<<E, TPB, 0, stream>>>(blockHist, counts, numBlocks, E);
    k_pos_scatter<<<N, TPB, 0, stream>>>(eidx, scale, blockHist, counts, x,
                                         out_rowix, out_scale, out_cum, out_x,
                                         NK, E, K, H);
}